// Round 2
// baseline (1192.807 us; speedup 1.0000x reference)
//
#include <hip/hip_runtime.h>

#define NEG_SLOPE 0.2f

static constexpr int Hh = 4;
static constexpr int Nn = 50000;
static constexpr int Ee = 1600000;
static constexpr int D  = 32;
static constexpr int NR = Hh * Nn;                        // 200000 rows (head-major)
static constexpr int NSB = (NR + 255) / 256;              // 782 scan blocks

// ---------------------------------------------------------------------------
// Kernel 1: xl = x @ W_l, xr = x @ W_r per head. 8 nodes x 32 ch per block.
// ---------------------------------------------------------------------------
__global__ void transform_kernel(const float* __restrict__ x,
                                 const float* __restrict__ Wl,
                                 const float* __restrict__ Wr,
                                 float* __restrict__ xl,
                                 float* __restrict__ xr) {
    __shared__ float wl_s[D * D];
    __shared__ float wr_s[D * D];
    const int h   = blockIdx.y;
    const int tid = threadIdx.x;
    for (int i = tid; i < D * D; i += 256) {
        wl_s[i] = Wl[h * D * D + i];
        wr_s[i] = Wr[h * D * D + i];
    }
    __syncthreads();

    const int node = blockIdx.x * 8 + (tid >> 5);
    const int c    = tid & 31;
    if (node >= Nn) return;

    const float* xrow = x + ((size_t)h * Nn + node) * D;
    float al = 0.f, ar = 0.f;
#pragma unroll
    for (int k = 0; k < D; ++k) {
        const float xv = xrow[k];
        al = fmaf(xv, wl_s[k * D + c], al);
        ar = fmaf(xv, wr_s[k * D + c], ar);
    }
    const size_t o = ((size_t)h * Nn + node) * D + c;
    xl[o] = al;
    xr[o] = ar;
}

// ---------------------------------------------------------------------------
// CSR build: histogram of dst (int atomics on 0.8 MB, L2-resident)
// ---------------------------------------------------------------------------
__global__ void hist_kernel(const int* __restrict__ ei, int* __restrict__ counts) {
    const int e = blockIdx.x * 256 + threadIdx.x;
    const int h = blockIdx.y;
    if (e >= Ee) return;
    const int dst = ei[(size_t)h * 2 * Ee + Ee + e];
    atomicAdd(&counts[h * Nn + dst], 1);
}

// Scan pass 1: per-256-block sums
__global__ void scan1_kernel(const int* __restrict__ counts, int* __restrict__ bsum) {
    __shared__ int s[256];
    const int tid = threadIdx.x;
    const int i   = blockIdx.x * 256 + tid;
    s[tid] = (i < NR) ? counts[i] : 0;
    __syncthreads();
    for (int o = 128; o; o >>= 1) {
        if (tid < o) s[tid] += s[tid + o];
        __syncthreads();
    }
    if (tid == 0) bsum[blockIdx.x] = s[0];
}

// Scan pass 2: exclusive scan of block sums (NSB <= 1024), one block
__global__ void scan2_kernel(int* __restrict__ bsum) {
    __shared__ int s[1024];
    const int tid = threadIdx.x;
    s[tid] = (tid < NSB) ? bsum[tid] : 0;
    __syncthreads();
    for (int o = 1; o < 1024; o <<= 1) {
        const int v = (tid >= o) ? s[tid - o] : 0;
        __syncthreads();
        s[tid] += v;
        __syncthreads();
    }
    if (tid < NSB) bsum[tid] = tid ? s[tid - 1] : 0;
}

// Scan pass 3: block-local exclusive scan + block offset -> offs, curs
__global__ void scan3_kernel(const int* __restrict__ counts, const int* __restrict__ bsum,
                             int* __restrict__ offs, int* __restrict__ curs) {
    __shared__ int s[256];
    const int tid = threadIdx.x;
    const int i   = blockIdx.x * 256 + tid;
    const int v   = (i < NR) ? counts[i] : 0;
    s[tid] = v;
    __syncthreads();
    for (int o = 1; o < 256; o <<= 1) {
        const int t = (tid >= o) ? s[tid - o] : 0;
        __syncthreads();
        s[tid] += t;
        __syncthreads();
    }
    if (i < NR) {
        const int excl = s[tid] - v + bsum[blockIdx.x];
        offs[i] = excl;
        curs[i] = excl;
    }
}

// Scatter: counting-sort placement of src by dst bin
__global__ void scatter_kernel(const int* __restrict__ ei, int* __restrict__ curs,
                               int* __restrict__ ssrc) {
    const int e = blockIdx.x * 256 + threadIdx.x;
    const int h = blockIdx.y;
    if (e >= Ee) return;
    const int src = ei[(size_t)h * 2 * Ee + e];
    const int dst = ei[(size_t)h * 2 * Ee + Ee + e];
    const int pos = atomicAdd(&curs[h * Nn + dst], 1);
    ssrc[pos] = src;
}

// ---------------------------------------------------------------------------
// Accumulate: 32 lanes per (head,dst) row. Register accumulation, no atomics.
// Self-loop handled inline. Fused denom/div/bias. Single coalesced store.
// ---------------------------------------------------------------------------
__global__ void accum_kernel(const int* __restrict__ offs, const int* __restrict__ counts,
                             const int* __restrict__ ssrc,
                             const float* __restrict__ xl, const float* __restrict__ xr,
                             const float* __restrict__ att, const float* __restrict__ bias,
                             float* __restrict__ out) {
    const int tid = threadIdx.x;
    const int r   = blockIdx.x * 8 + (tid >> 5);
    const int c   = tid & 31;
    if (r >= NR) return;
    const int h = r / Nn;
    const int n = r - h * Nn;

    const float attc = att[h * D + c];
    const float xrd  = xr[(size_t)r * D + c];
    const float xld  = xl[(size_t)r * D + c];

    // self-loop (src == dst)
    float hv = xld + xrd;
    float lv = hv > 0.f ? hv : NEG_SLOPE * hv;
    float p  = lv * attc;
#pragma unroll
    for (int o = 16; o; o >>= 1) p += __shfl_xor(p, o);
    float w   = __expf(p);
    float acc = w * xld;
    float den = w;

    const int beg = offs[r];
    const int end = beg + counts[r];
    for (int base = beg; base < end; base += 32) {
        int idx = base + c;
        if (idx >= end) idx = end - 1;          // clamp (safe: loop implies end>beg)
        const int sv = ssrc[idx];
        const int m  = (end - base) < 32 ? (end - base) : 32;
        for (int j = 0; j < m; ++j) {
            const int s = __shfl(sv, j, 32);
            const float xls = xl[((size_t)h * Nn + s) * D + c];
            const float h2  = xls + xrd;
            const float l2  = h2 > 0.f ? h2 : NEG_SLOPE * h2;
            float p2 = l2 * attc;
#pragma unroll
            for (int o = 16; o; o >>= 1) p2 += __shfl_xor(p2, o);
            const float w2 = __expf(p2);
            acc = fmaf(w2, xls, acc);
            den += w2;
        }
    }
    out[(size_t)n * (Hh * D) + h * D + c] = acc / den + bias[h * D + c];
}

extern "C" void kernel_launch(void* const* d_in, const int* in_sizes, int n_in,
                              void* d_out, int out_size, void* d_ws, size_t ws_size,
                              hipStream_t stream) {
    const float* x    = (const float*)d_in[0];
    const int*   ei   = (const int*)d_in[1];
    const float* Wl   = (const float*)d_in[2];
    const float* Wr   = (const float*)d_in[3];
    const float* att  = (const float*)d_in[4];
    const float* bias = (const float*)d_in[5];
    float* out = (float*)d_out;

    // workspace layout (all 4-byte elems):
    // xl[H*N*D] | xr[H*N*D] | ssrc[H*E] | counts[NR] | offs[NR] | curs[NR] | bsum[1024]
    float* xl    = (float*)d_ws;
    float* xr    = xl + (size_t)Hh * Nn * D;
    int*   ssrc  = (int*)(xr + (size_t)Hh * Nn * D);
    int*   counts = ssrc + (size_t)Hh * Ee;
    int*   offs  = counts + NR;
    int*   curs  = offs + NR;
    int*   bsum  = curs + NR;

    hipMemsetAsync(counts, 0, NR * sizeof(int), stream);

    dim3 gT((Nn + 7) / 8, Hh);
    transform_kernel<<<gT, 256, 0, stream>>>(x, Wl, Wr, xl, xr);

    dim3 gE((Ee + 255) / 256, Hh);
    hist_kernel<<<gE, 256, 0, stream>>>(ei, counts);

    scan1_kernel<<<NSB, 256, 0, stream>>>(counts, bsum);
    scan2_kernel<<<1, 1024, 0, stream>>>(bsum);
    scan3_kernel<<<NSB, 256, 0, stream>>>(counts, bsum, offs, curs);

    scatter_kernel<<<gE, 256, 0, stream>>>(ei, curs, ssrc);

    accum_kernel<<<(NR + 7) / 8, 256, 0, stream>>>(offs, counts, ssrc, xl, xr,
                                                   att, bias, out);
}